// Round 1
// baseline (378.820 us; speedup 1.0000x reference)
//
#include <hip/hip_runtime.h>
#include <stdint.h>

// Problem constants (fixed shapes from setup_inputs)
#define S_LEN  2048
#define B_DIM  8
#define E_DIM  1024
#define BE     (B_DIM * E_DIM)      // 8192  (one time-step's elements)
#define M_ROWS (S_LEN * B_DIM)      // 16384 (GEMM M)
#define NCHUNK 64
#define CLEN   (S_LEN / NCHUNK)     // 32

typedef __attribute__((ext_vector_type(8))) short bf16x8;  // 8 bf16 (4 VGPRs)
typedef __attribute__((ext_vector_type(4))) float f32x4;

__device__ __forceinline__ unsigned short f2bf(float f) {
    // round-to-nearest-even f32 -> bf16 (no NaN inputs expected)
    unsigned int u = __float_as_uint(f);
    u += 0x7FFFu + ((u >> 16) & 1u);
    return (unsigned short)(u >> 16);
}

// ---------------------------------------------------------------------------
// 1. token-shift mix: xk = mk*x + (1-mk)*x_prev, xv likewise; output bf16
// ---------------------------------------------------------------------------
__global__ __launch_bounds__(256) void mix_kernel(
    const float* __restrict__ x, const float* __restrict__ tmrkv,
    unsigned short* __restrict__ xk, unsigned short* __restrict__ xv)
{
    int i = blockIdx.x * 256 + threadIdx.x;           // float4 index
    const float4* x4 = (const float4*)x;
    float4 xc = x4[i];
    float4 xp = make_float4(0.f, 0.f, 0.f, 0.f);
    if (i >= BE / 4) xp = x4[i - BE / 4];             // x_prev = shift by one t
    int e4 = i & (E_DIM / 4 - 1);
    float4 mk = ((const float4*)(tmrkv + E_DIM))[e4];
    float4 mv = ((const float4*)(tmrkv + 2 * E_DIM))[e4];
    ushort4 ok, ov;
    ok.x = f2bf(mk.x * xc.x + (1.f - mk.x) * xp.x);
    ok.y = f2bf(mk.y * xc.y + (1.f - mk.y) * xp.y);
    ok.z = f2bf(mk.z * xc.z + (1.f - mk.z) * xp.z);
    ok.w = f2bf(mk.w * xc.w + (1.f - mk.w) * xp.w);
    ov.x = f2bf(mv.x * xc.x + (1.f - mv.x) * xp.x);
    ov.y = f2bf(mv.y * xc.y + (1.f - mv.y) * xp.y);
    ov.z = f2bf(mv.z * xc.z + (1.f - mv.z) * xp.z);
    ov.w = f2bf(mv.w * xc.w + (1.f - mv.w) * xp.w);
    ((ushort4*)xk)[i] = ok;
    ((ushort4*)xv)[i] = ov;
}

// ---------------------------------------------------------------------------
// 2. cast + transpose weights f32[K][N] -> bf16[N][K]  (B^T layout for GEMM)
// ---------------------------------------------------------------------------
__global__ __launch_bounds__(256) void cast_transpose_k(
    const float* __restrict__ in, unsigned short* __restrict__ out)
{
    __shared__ float tile[32][33];
    int bx = blockIdx.x * 32, by = blockIdx.y * 32;
    int tx = threadIdx.x, ty = threadIdx.y;           // block (32, 8)
    #pragma unroll
    for (int i = 0; i < 32; i += 8)
        tile[ty + i][tx] = in[(size_t)(by + ty + i) * E_DIM + bx + tx];
    __syncthreads();
    #pragma unroll
    for (int i = 0; i < 32; i += 8)
        out[(size_t)(bx + ty + i) * E_DIM + by + tx] = f2bf(tile[tx][ty + i]);
}

// ---------------------------------------------------------------------------
// 3. bf16 MFMA GEMM: C[M][N] f32 = A[M][K] bf16 @ (BT[N][K] bf16)^T
//    128x128 tile, BK=32, 16x16x32 MFMA, global_load_lds width-16 staging
// ---------------------------------------------------------------------------
#define BM 128
#define BN 128
#define BK 32

__global__ __launch_bounds__(256) void gemm_bf16_bt(
    const unsigned short* __restrict__ A,
    const unsigned short* __restrict__ BT,
    float* __restrict__ C, int M, int N, int K)
{
    __shared__ __align__(16) unsigned short As[BM * BK];  // [128][32] rows of 64B
    __shared__ __align__(16) unsigned short Bs[BN * BK];  // [128][32]
    const int tid  = threadIdx.x;
    const int wave = tid >> 6, lane = tid & 63;
    const int bm = blockIdx.x * BM, bn = blockIdx.y * BN;
    const int wr = (wave >> 1) * 64, wc = (wave & 1) * 64; // wave's 64x64 region
    const int lrow = lane & 15, lq = lane >> 4;

    f32x4 acc[4][4];
    #pragma unroll
    for (int i = 0; i < 4; ++i)
        #pragma unroll
        for (int j = 0; j < 4; ++j)
            acc[i][j] = (f32x4){0.f, 0.f, 0.f, 0.f};

    const int nk = K / BK;
    for (int kt = 0; kt < nk; ++kt) {
        __syncthreads();                               // prev reads done
        const int kk = kt * BK;
        // stage A and B tiles: 512 chunks of 16B each; wave-uniform LDS base
        #pragma unroll
        for (int s = 0; s < 2; ++s) {
            int chunk = s * 256 + wave * 64 + lane;    // 0..511
            int row = chunk >> 2;                      // 0..127
            int cb  = (chunk & 3) * 16;                // byte within 64B row
            const char* ga = (const char*)(A  + (size_t)(bm + row) * K + kk) + cb;
            const char* gb = (const char*)(BT + (size_t)(bn + row) * K + kk) + cb;
            char* la = (char*)As + s * 4096 + wave * 1024;
            char* lb = (char*)Bs + s * 4096 + wave * 1024;
            __builtin_amdgcn_global_load_lds(
                (const __attribute__((address_space(1))) unsigned int*)ga,
                (__attribute__((address_space(3))) unsigned int*)la, 16, 0, 0);
            __builtin_amdgcn_global_load_lds(
                (const __attribute__((address_space(1))) unsigned int*)gb,
                (__attribute__((address_space(3))) unsigned int*)lb, 16, 0, 0);
        }
        __syncthreads();                               // drains vmcnt + barrier

        bf16x8 af[4], bf[4];
        #pragma unroll
        for (int i = 0; i < 4; ++i)
            af[i] = *(const bf16x8*)&As[(wr + i * 16 + lrow) * BK + lq * 8];
        #pragma unroll
        for (int j = 0; j < 4; ++j)
            bf[j] = *(const bf16x8*)&Bs[(wc + j * 16 + lrow) * BK + lq * 8];
        #pragma unroll
        for (int i = 0; i < 4; ++i)
            #pragma unroll
            for (int j = 0; j < 4; ++j)
                acc[i][j] = __builtin_amdgcn_mfma_f32_16x16x32_bf16(
                    af[i], bf[j], acc[i][j], 0, 0, 0);
    }

    // epilogue: D[row=(lane>>4)*4+r][col=lane&15] per 16x16 subtile
    #pragma unroll
    for (int i = 0; i < 4; ++i)
        #pragma unroll
        for (int j = 0; j < 4; ++j)
            #pragma unroll
            for (int r = 0; r < 4; ++r) {
                int row = bm + wr + i * 16 + lq * 4 + r;
                int col = bn + wc + j * 16 + lrow;
                C[(size_t)row * N + col] = acc[i][j][r];
            }
}

// ---------------------------------------------------------------------------
// 4. WKV associative scan, chunked 3-pass. Element: (v,1,w,k); combine:
//    p'=max(p_l+w_r, p_r); a'=a_l*e1+a_r*e2; b'=b_l*e1+b_r*e2
// ---------------------------------------------------------------------------
__global__ __launch_bounds__(256) void scan_pass1(
    const float* __restrict__ k, const float* __restrict__ v,
    const float* __restrict__ tdec,
    float* __restrict__ sA, float* __restrict__ sB, float* __restrict__ sP)
{
    int g  = blockIdx.x * 256 + threadIdx.x;   // g = c*BE + ch
    int ch = g & (BE - 1);
    int c  = g >> 13;
    float w = tdec[ch & (E_DIM - 1)];
    size_t idx = (size_t)c * CLEN * BE + ch;
    float a = v[idx], bsum = 1.0f, p = k[idx];
    for (int j = 1; j < CLEN; ++j) {
        idx += BE;
        float kt = k[idx], vt = v[idx];
        float pw = p + w;
        float pn = fmaxf(pw, kt);
        float e1 = __expf(pw - pn), e2 = __expf(kt - pn);
        a    = a * e1 + vt * e2;
        bsum = bsum * e1 + e2;
        p    = pn;
    }
    sA[g] = a; sB[g] = bsum; sP[g] = p;
}

__global__ __launch_bounds__(256) void scan_pass2(
    const float* __restrict__ tdec,
    float* __restrict__ sA, float* __restrict__ sB, float* __restrict__ sP)
{
    int ch = blockIdx.x * 256 + threadIdx.x;   // one thread per channel
    float w  = tdec[ch & (E_DIM - 1)];
    float Lw = (float)CLEN * w;                // chunk's total decay
    float pa = 0.f, pb = 0.f, pp = -__builtin_inff();  // identity
    for (int c = 0; c < NCHUNK; ++c) {
        int idx = c * BE + ch;
        float ra = sA[idx], rb = sB[idx], rp = sP[idx];
        sA[idx] = pa; sB[idx] = pb; sP[idx] = pp;      // exclusive prefix
        float pw = pp + Lw;
        float pn = fmaxf(pw, rp);
        float e1 = __expf(pw - pn), e2 = __expf(rp - pn);
        pa = pa * e1 + ra * e2;
        pb = pb * e1 + rb * e2;
        pp = pn;
    }
}

__global__ __launch_bounds__(256) void scan_pass3(
    const float* __restrict__ k, const float* __restrict__ v,
    const float* __restrict__ tdec, const float* __restrict__ tfir,
    const float* __restrict__ sA, const float* __restrict__ sB,
    const float* __restrict__ sP, unsigned short* __restrict__ rwkv)
{
    int g  = blockIdx.x * 256 + threadIdx.x;
    int ch = g & (BE - 1);
    int c  = g >> 13;
    int e  = ch & (E_DIM - 1);
    float w  = tdec[e];
    float u2 = tfir[e] + w;                    // time_first + time_decay
    float a = sA[g], bsum = sB[g], p = sP[g];  // carry-in (exclusive prefix)
    size_t idx = (size_t)c * CLEN * BE + ch;
    for (int j = 0; j < CLEN; ++j) {
        float kt = k[idx], vt = v[idx];
        // inclusive state update
        float pw = p + w;
        float pn = fmaxf(pw, kt);
        float e1 = __expf(pw - pn), e2 = __expf(kt - pn);
        a    = a * e1 + vt * e2;
        bsum = bsum * e1 + e2;
        p    = pn;
        // bonus-mix output: exp_mix_frac(p, k+u+w, a, b, v, 1)
        float kb = kt + u2;
        float q  = fmaxf(p, kb);
        float f1 = __expf(p - q), f2 = __expf(kb - q);
        rwkv[idx] = f2bf((a * f1 + vt * f2) / (bsum * f1 + f2));
        idx += BE;
    }
}

// ---------------------------------------------------------------------------
extern "C" void kernel_launch(void* const* d_in, const int* in_sizes, int n_in,
                              void* d_out, int out_size, void* d_ws, size_t ws_size,
                              hipStream_t stream)
{
    const float* x     = (const float*)d_in[0];
    const float* tmrkv = (const float*)d_in[1];
    const float* Wk    = (const float*)d_in[2];
    const float* Wv    = (const float*)d_in[3];
    const float* tdec  = (const float*)d_in[4];
    const float* tfir  = (const float*)d_in[5];
    const float* Wout  = (const float*)d_in[6];
    float* out = (float*)d_out;

    // workspace layout (198 MiB): xk | xv | k | v | WkT | WvT | WoutT
    // reuse: rwkv -> xk space (dead after gemm_k); scan scratch -> xv space
    char* ws = (char*)d_ws;
    const size_t SZ_XKV = (size_t)M_ROWS * E_DIM * 2;   // 32 MiB
    const size_t SZ_KV  = (size_t)M_ROWS * E_DIM * 4;   // 64 MiB
    unsigned short* xk   = (unsigned short*)(ws);
    unsigned short* xv   = (unsigned short*)(ws + SZ_XKV);
    float* kbuf          = (float*)(ws + 2 * SZ_XKV);
    float* vbuf          = (float*)(ws + 2 * SZ_XKV + SZ_KV);
    unsigned short* WkT  = (unsigned short*)(ws + 2 * SZ_XKV + 2 * SZ_KV);
    unsigned short* WvT  = WkT + (size_t)E_DIM * E_DIM;
    unsigned short* WoutT= WvT + (size_t)E_DIM * E_DIM;
    float* sA = (float*)xv;                    // 2 MiB each, xv dead by then
    float* sB = sA + (size_t)NCHUNK * BE;
    float* sP = sB + (size_t)NCHUNK * BE;
    unsigned short* rwkv = xk;                 // xk dead after gemm_k

    // 1. mix (reads x; writes xk, xv bf16)
    mix_kernel<<<(M_ROWS * E_DIM / 4) / 256, 256, 0, stream>>>(x, tmrkv, xk, xv);

    // 2. weight casts (f32 [K][N] -> bf16 [N][K])
    dim3 tb(32, 8), tg(E_DIM / 32, E_DIM / 32);
    cast_transpose_k<<<tg, tb, 0, stream>>>(Wk,   WkT);
    cast_transpose_k<<<tg, tb, 0, stream>>>(Wv,   WvT);
    cast_transpose_k<<<tg, tb, 0, stream>>>(Wout, WoutT);

    // 3. k = xk @ Wk, v = xv @ Wv  (f32 out)
    dim3 gg(M_ROWS / BM, E_DIM / BN);
    gemm_bf16_bt<<<gg, 256, 0, stream>>>(xk, WkT, kbuf, M_ROWS, E_DIM, E_DIM);
    gemm_bf16_bt<<<gg, 256, 0, stream>>>(xv, WvT, vbuf, M_ROWS, E_DIM, E_DIM);

    // 4. chunked associative scan -> rwkv bf16
    scan_pass1<<<(NCHUNK * BE) / 256, 256, 0, stream>>>(kbuf, vbuf, tdec, sA, sB, sP);
    scan_pass2<<<BE / 256, 256, 0, stream>>>(tdec, sA, sB, sP);
    scan_pass3<<<(NCHUNK * BE) / 256, 256, 0, stream>>>(kbuf, vbuf, tdec, tfir,
                                                        sA, sB, sP, rwkv);

    // 5. out = rwkv @ Wout
    gemm_bf16_bt<<<gg, 256, 0, stream>>>(rwkv, WoutT, out, M_ROWS, E_DIM, E_DIM);
}

// Round 2
// 346.319 us; speedup vs baseline: 1.0938x; 1.0938x over previous
//
#include <hip/hip_runtime.h>
#include <stdint.h>

// Problem constants (fixed shapes from setup_inputs)
#define S_LEN  2048
#define B_DIM  8
#define E_DIM  1024
#define BE     (B_DIM * E_DIM)      // 8192  (one time-step's elements)
#define M_ROWS (S_LEN * B_DIM)      // 16384 (GEMM M)
#define NCHUNK 64
#define CLEN   (S_LEN / NCHUNK)     // 32

typedef __attribute__((ext_vector_type(8))) short bf16x8;  // 8 bf16 (4 VGPRs)
typedef __attribute__((ext_vector_type(4))) float f32x4;

__device__ __forceinline__ unsigned short f2bf(float f) {
    // round-to-nearest-even f32 -> bf16 (no NaN inputs expected)
    unsigned int u = __float_as_uint(f);
    u += 0x7FFFu + ((u >> 16) & 1u);
    return (unsigned short)(u >> 16);
}

// ---------------------------------------------------------------------------
// 1. token-shift mix: xk = mk*x + (1-mk)*x_prev, xv likewise; output bf16
// ---------------------------------------------------------------------------
__global__ __launch_bounds__(256) void mix_kernel(
    const float* __restrict__ x, const float* __restrict__ tmrkv,
    unsigned short* __restrict__ xk, unsigned short* __restrict__ xv)
{
    int i = blockIdx.x * 256 + threadIdx.x;           // float4 index
    const float4* x4 = (const float4*)x;
    float4 xc = x4[i];
    float4 xp = make_float4(0.f, 0.f, 0.f, 0.f);
    if (i >= BE / 4) xp = x4[i - BE / 4];             // x_prev = shift by one t
    int e4 = i & (E_DIM / 4 - 1);
    float4 mk = ((const float4*)(tmrkv + E_DIM))[e4];
    float4 mv = ((const float4*)(tmrkv + 2 * E_DIM))[e4];
    ushort4 ok, ov;
    ok.x = f2bf(mk.x * xc.x + (1.f - mk.x) * xp.x);
    ok.y = f2bf(mk.y * xc.y + (1.f - mk.y) * xp.y);
    ok.z = f2bf(mk.z * xc.z + (1.f - mk.z) * xp.z);
    ok.w = f2bf(mk.w * xc.w + (1.f - mk.w) * xp.w);
    ov.x = f2bf(mv.x * xc.x + (1.f - mv.x) * xp.x);
    ov.y = f2bf(mv.y * xc.y + (1.f - mv.y) * xp.y);
    ov.z = f2bf(mv.z * xc.z + (1.f - mv.z) * xp.z);
    ov.w = f2bf(mv.w * xc.w + (1.f - mv.w) * xp.w);
    ((ushort4*)xk)[i] = ok;
    ((ushort4*)xv)[i] = ov;
}

// ---------------------------------------------------------------------------
// 2. cast + transpose weights f32[K][N] -> bf16[N][K]; 3 matrices via grid z
// ---------------------------------------------------------------------------
__global__ __launch_bounds__(256) void cast_transpose_k(
    const float* __restrict__ w0, const float* __restrict__ w1,
    const float* __restrict__ w2,
    unsigned short* __restrict__ o0, unsigned short* __restrict__ o1,
    unsigned short* __restrict__ o2)
{
    const float* in = blockIdx.z == 0 ? w0 : (blockIdx.z == 1 ? w1 : w2);
    unsigned short* out = blockIdx.z == 0 ? o0 : (blockIdx.z == 1 ? o1 : o2);
    __shared__ float tile[32][33];
    int bx = blockIdx.x * 32, by = blockIdx.y * 32;
    int tx = threadIdx.x, ty = threadIdx.y;           // block (32, 8)
    #pragma unroll
    for (int i = 0; i < 32; i += 8)
        tile[ty + i][tx] = in[(size_t)(by + ty + i) * E_DIM + bx + tx];
    __syncthreads();
    #pragma unroll
    for (int i = 0; i < 32; i += 8)
        out[(size_t)(bx + ty + i) * E_DIM + by + tx] = f2bf(tile[tx][ty + i]);
}

// ---------------------------------------------------------------------------
// 3. bf16 MFMA GEMM: C[M][N] f32 = A[M][K] bf16 @ (BT[N][K] bf16)^T
//    128x128 tile, BK=64 (128B rows = bank-stride aligned), XOR-8 chunk
//    swizzle (lds_chunk = gchunk ^ (row&7)) -> conflict-free ds_read_b128.
//    Swizzle is realized in the staging lane->global-chunk mapping since
//    global_load_lds dest is wave-uniform base + lane*16.
// ---------------------------------------------------------------------------
#define BM 128
#define BN 128
#define BK 64

__global__ __launch_bounds__(256) void gemm_bf16_bt(
    const unsigned short* __restrict__ A,
    const unsigned short* __restrict__ BT,
    float* __restrict__ C, int M, int N, int K)
{
    __shared__ __align__(16) unsigned short As[BM * BK];  // 16 KiB, 128B rows
    __shared__ __align__(16) unsigned short Bs[BN * BK];  // 16 KiB
    const int tid  = threadIdx.x;
    const int wave = tid >> 6, lane = tid & 63;
    const int bm = blockIdx.x * BM, bn = blockIdx.y * BN;
    const int wr = (wave >> 1) * 64, wc = (wave & 1) * 64; // wave's 64x64 region
    const int lrow = lane & 15, lq = lane >> 4;

    f32x4 acc[4][4];
    #pragma unroll
    for (int i = 0; i < 4; ++i)
        #pragma unroll
        for (int j = 0; j < 4; ++j)
            acc[i][j] = (f32x4){0.f, 0.f, 0.f, 0.f};

    const int nk = K / BK;
    for (int kt = 0; kt < nk; ++kt) {
        __syncthreads();                               // prev reads done
        const int kk = kt * BK;
        // stage A and B tiles: 1024 chunks of 16B each per matrix.
        // lds chunk idx = s*256 + wave*64 + lane (HW: wave base + lane*16).
        // row = idx>>3, lds col c' = idx&7, global chunk gc = c' ^ (row&7).
        #pragma unroll
        for (int s = 0; s < 4; ++s) {
            int idx = s * 256 + wave * 64 + lane;
            int r   = idx >> 3;
            int gc  = (idx & 7) ^ (r & 7);
            const char* ga = (const char*)(A  + (size_t)(bm + r) * K + kk) + gc * 16;
            const char* gb = (const char*)(BT + (size_t)(bn + r) * K + kk) + gc * 16;
            char* la = (char*)As + s * 4096 + wave * 1024;   // wave-uniform
            char* lb = (char*)Bs + s * 4096 + wave * 1024;
            __builtin_amdgcn_global_load_lds(
                (const __attribute__((address_space(1))) unsigned int*)ga,
                (__attribute__((address_space(3))) unsigned int*)la, 16, 0, 0);
            __builtin_amdgcn_global_load_lds(
                (const __attribute__((address_space(1))) unsigned int*)gb,
                (__attribute__((address_space(3))) unsigned int*)lb, 16, 0, 0);
        }
        __syncthreads();                               // drains vmcnt + barrier

        #pragma unroll
        for (int h = 0; h < 2; ++h) {                  // two K=32 halves
            bf16x8 af[4], bf[4];
            #pragma unroll
            for (int i = 0; i < 4; ++i) {
                int R = wr + i * 16 + lrow;
                af[i] = *(const bf16x8*)&As[R * BK + (((h << 2) | lq) ^ (R & 7)) * 8];
            }
            #pragma unroll
            for (int j = 0; j < 4; ++j) {
                int R = wc + j * 16 + lrow;
                bf[j] = *(const bf16x8*)&Bs[R * BK + (((h << 2) | lq) ^ (R & 7)) * 8];
            }
            #pragma unroll
            for (int i = 0; i < 4; ++i)
                #pragma unroll
                for (int j = 0; j < 4; ++j)
                    acc[i][j] = __builtin_amdgcn_mfma_f32_16x16x32_bf16(
                        af[i], bf[j], acc[i][j], 0, 0, 0);
        }
    }

    // epilogue: D[row=(lane>>4)*4+r][col=lane&15] per 16x16 subtile
    #pragma unroll
    for (int i = 0; i < 4; ++i)
        #pragma unroll
        for (int j = 0; j < 4; ++j)
            #pragma unroll
            for (int r = 0; r < 4; ++r) {
                int row = bm + wr + i * 16 + lq * 4 + r;
                int col = bn + wc + j * 16 + lrow;
                C[(size_t)row * N + col] = acc[i][j][r];
            }
}

// ---------------------------------------------------------------------------
// 4. WKV associative scan, chunked 3-pass. Element: (v,1,w,k); combine:
//    p'=max(p_l+w_r, p_r); a'=a_l*e1+a_r*e2; b'=b_l*e1+b_r*e2
// ---------------------------------------------------------------------------
__global__ __launch_bounds__(256) void scan_pass1(
    const float* __restrict__ k, const float* __restrict__ v,
    const float* __restrict__ tdec,
    float* __restrict__ sA, float* __restrict__ sB, float* __restrict__ sP)
{
    int g  = blockIdx.x * 256 + threadIdx.x;   // g = c*BE + ch
    int ch = g & (BE - 1);
    int c  = g >> 13;
    float w = tdec[ch & (E_DIM - 1)];
    size_t idx = (size_t)c * CLEN * BE + ch;
    float a = v[idx], bsum = 1.0f, p = k[idx];
    for (int j = 1; j < CLEN; ++j) {
        idx += BE;
        float kt = k[idx], vt = v[idx];
        float pw = p + w;
        float pn = fmaxf(pw, kt);
        float e1 = __expf(pw - pn), e2 = __expf(kt - pn);
        a    = a * e1 + vt * e2;
        bsum = bsum * e1 + e2;
        p    = pn;
    }
    sA[g] = a; sB[g] = bsum; sP[g] = p;
}

// Wave-parallel cross-chunk exclusive scan: block = 64 channels x 64 chunks.
// LDS transpose -> lane-per-chunk Hillis-Steele shuffle scan (6 steps).
__global__ __launch_bounds__(256) void scan_pass2(
    const float* __restrict__ tdec,
    float* __restrict__ sA, float* __restrict__ sB, float* __restrict__ sP)
{
    __shared__ float tA[64 * 65], tB[64 * 65], tP[64 * 65];
    const int t   = threadIdx.x;
    const int ch0 = blockIdx.x * 64;
    const int chl = t & 63;
    const int cq  = t >> 6;                    // 0..3
    #pragma unroll 4
    for (int cc = 0; cc < 16; ++cc) {
        int c = cq * 16 + cc;
        int idx = c * BE + ch0 + chl;
        tA[chl * 65 + c] = sA[idx];
        tB[chl * 65 + c] = sB[idx];
        tP[chl * 65 + c] = sP[idx];
    }
    __syncthreads();
    const int lane = t & 63, wave = t >> 6;
    for (int i = 0; i < 16; ++i) {
        int ch = wave * 16 + i;                // local channel 0..63
        float w = tdec[(ch0 + ch) & (E_DIM - 1)];
        float a = tA[ch * 65 + lane];
        float b = tB[ch * 65 + lane];
        float p = tP[ch * 65 + lane];
        float W = (float)CLEN * w;             // accumulated decay of this span
        #pragma unroll
        for (int d = 1; d < 64; d <<= 1) {
            float a_l = __shfl_up(a, d);
            float b_l = __shfl_up(b, d);
            float p_l = __shfl_up(p, d);
            float W_l = __shfl_up(W, d);
            if (lane >= d) {
                float pw = p_l + W;            // left.p + right.Wacc
                float pn = fmaxf(pw, p);
                float e1 = __expf(pw - pn), e2 = __expf(p - pn);
                a = a_l * e1 + a * e2;
                b = b_l * e1 + b * e2;
                p = pn;
                W = W_l + W;
            }
        }
        // exclusive = inclusive shifted up by one; identity at chunk 0
        float ea = __shfl_up(a, 1);
        float eb = __shfl_up(b, 1);
        float ep = __shfl_up(p, 1);
        if (lane == 0) { ea = 0.f; eb = 0.f; ep = -__builtin_inff(); }
        tA[ch * 65 + lane] = ea;
        tB[ch * 65 + lane] = eb;
        tP[ch * 65 + lane] = ep;
    }
    __syncthreads();
    #pragma unroll 4
    for (int cc = 0; cc < 16; ++cc) {
        int c = cq * 16 + cc;
        int idx = c * BE + ch0 + chl;
        sA[idx] = tA[chl * 65 + c];
        sB[idx] = tB[chl * 65 + c];
        sP[idx] = tP[chl * 65 + c];
    }
}

__global__ __launch_bounds__(256) void scan_pass3(
    const float* __restrict__ k, const float* __restrict__ v,
    const float* __restrict__ tdec, const float* __restrict__ tfir,
    const float* __restrict__ sA, const float* __restrict__ sB,
    const float* __restrict__ sP, unsigned short* __restrict__ rwkv)
{
    int g  = blockIdx.x * 256 + threadIdx.x;
    int ch = g & (BE - 1);
    int c  = g >> 13;
    int e  = ch & (E_DIM - 1);
    float w  = tdec[e];
    float u2 = tfir[e] + w;                    // time_first + time_decay
    float a = sA[g], bsum = sB[g], p = sP[g];  // carry-in (exclusive prefix)
    size_t idx = (size_t)c * CLEN * BE + ch;
    for (int j = 0; j < CLEN; ++j) {
        float kt = k[idx], vt = v[idx];
        // inclusive state update
        float pw = p + w;
        float pn = fmaxf(pw, kt);
        float e1 = __expf(pw - pn), e2 = __expf(kt - pn);
        a    = a * e1 + vt * e2;
        bsum = bsum * e1 + e2;
        p    = pn;
        // bonus-mix output: exp_mix_frac(p, k+u+w, a, b, v, 1)
        float kb = kt + u2;
        float q  = fmaxf(p, kb);
        float f1 = __expf(p - q), f2 = __expf(kb - q);
        rwkv[idx] = f2bf((a * f1 + vt * f2) / (bsum * f1 + f2));
        idx += BE;
    }
}

// ---------------------------------------------------------------------------
extern "C" void kernel_launch(void* const* d_in, const int* in_sizes, int n_in,
                              void* d_out, int out_size, void* d_ws, size_t ws_size,
                              hipStream_t stream)
{
    const float* x     = (const float*)d_in[0];
    const float* tmrkv = (const float*)d_in[1];
    const float* Wk    = (const float*)d_in[2];
    const float* Wv    = (const float*)d_in[3];
    const float* tdec  = (const float*)d_in[4];
    const float* tfir  = (const float*)d_in[5];
    const float* Wout  = (const float*)d_in[6];
    float* out = (float*)d_out;

    // workspace layout (198 MiB): xk | xv | k | v | WkT | WvT | WoutT
    // reuse: rwkv -> xk space (dead after gemm_k); scan scratch -> xv space
    char* ws = (char*)d_ws;
    const size_t SZ_XKV = (size_t)M_ROWS * E_DIM * 2;   // 32 MiB
    const size_t SZ_KV  = (size_t)M_ROWS * E_DIM * 4;   // 64 MiB
    unsigned short* xk   = (unsigned short*)(ws);
    unsigned short* xv   = (unsigned short*)(ws + SZ_XKV);
    float* kbuf          = (float*)(ws + 2 * SZ_XKV);
    float* vbuf          = (float*)(ws + 2 * SZ_XKV + SZ_KV);
    unsigned short* WkT  = (unsigned short*)(ws + 2 * SZ_XKV + 2 * SZ_KV);
    unsigned short* WvT  = WkT + (size_t)E_DIM * E_DIM;
    unsigned short* WoutT= WvT + (size_t)E_DIM * E_DIM;
    float* sA = (float*)xv;                    // 2 MiB each, xv dead by then
    float* sB = sA + (size_t)NCHUNK * BE;
    float* sP = sB + (size_t)NCHUNK * BE;
    unsigned short* rwkv = xk;                 // xk dead after gemm_k

    // 1. mix (reads x; writes xk, xv bf16)
    mix_kernel<<<(M_ROWS * E_DIM / 4) / 256, 256, 0, stream>>>(x, tmrkv, xk, xv);

    // 2. weight casts (f32 [K][N] -> bf16 [N][K]), one launch for all three
    dim3 tb(32, 8), tg(E_DIM / 32, E_DIM / 32, 3);
    cast_transpose_k<<<tg, tb, 0, stream>>>(Wk, Wv, Wout, WkT, WvT, WoutT);

    // 3. k = xk @ Wk, v = xv @ Wv  (f32 out)
    dim3 gg(M_ROWS / BM, E_DIM / BN);
    gemm_bf16_bt<<<gg, 256, 0, stream>>>(xk, WkT, kbuf, M_ROWS, E_DIM, E_DIM);
    gemm_bf16_bt<<<gg, 256, 0, stream>>>(xv, WvT, vbuf, M_ROWS, E_DIM, E_DIM);

    // 4. chunked associative scan -> rwkv bf16
    scan_pass1<<<(NCHUNK * BE) / 256, 256, 0, stream>>>(kbuf, vbuf, tdec, sA, sB, sP);
    scan_pass2<<<BE / 64, 256, 0, stream>>>(tdec, sA, sB, sP);
    scan_pass3<<<(NCHUNK * BE) / 256, 256, 0, stream>>>(kbuf, vbuf, tdec, tfir,
                                                        sA, sB, sP, rwkv);

    // 5. out = rwkv @ Wout
    gemm_bf16_bt<<<gg, 256, 0, stream>>>(rwkv, WoutT, out, M_ROWS, E_DIM, E_DIM);
}

// Round 3
// 336.953 us; speedup vs baseline: 1.1243x; 1.0278x over previous
//
#include <hip/hip_runtime.h>
#include <stdint.h>

// Problem constants (fixed shapes from setup_inputs)
#define S_LEN  2048
#define B_DIM  8
#define E_DIM  1024
#define BE     (B_DIM * E_DIM)      // 8192  (one time-step's elements)
#define M_ROWS (S_LEN * B_DIM)      // 16384 (GEMM M)
#define NCHUNK 64
#define CLEN   (S_LEN / NCHUNK)     // 32

typedef __attribute__((ext_vector_type(8))) short bf16x8;  // 8 bf16 (4 VGPRs)
typedef __attribute__((ext_vector_type(4))) float f32x4;

__device__ __forceinline__ unsigned short f2bf(float f) {
    // round-to-nearest-even f32 -> bf16 (no NaN inputs expected)
    unsigned int u = __float_as_uint(f);
    u += 0x7FFFu + ((u >> 16) & 1u);
    return (unsigned short)(u >> 16);
}
__device__ __forceinline__ float bf_lo(unsigned int u) {
    return __uint_as_float(u << 16);
}
__device__ __forceinline__ float bf_hi(unsigned int u) {
    return __uint_as_float(u & 0xFFFF0000u);
}

// ---------------------------------------------------------------------------
// 1. token-shift mix: xk = mk*x + (1-mk)*x_prev, xv likewise; output bf16
// ---------------------------------------------------------------------------
__global__ __launch_bounds__(256) void mix_kernel(
    const float* __restrict__ x, const float* __restrict__ tmrkv,
    unsigned short* __restrict__ xk, unsigned short* __restrict__ xv)
{
    int i = blockIdx.x * 256 + threadIdx.x;           // float4 index
    const float4* x4 = (const float4*)x;
    float4 xc = x4[i];
    float4 xp = make_float4(0.f, 0.f, 0.f, 0.f);
    if (i >= BE / 4) xp = x4[i - BE / 4];             // x_prev = shift by one t
    int e4 = i & (E_DIM / 4 - 1);
    float4 mk = ((const float4*)(tmrkv + E_DIM))[e4];
    float4 mv = ((const float4*)(tmrkv + 2 * E_DIM))[e4];
    ushort4 ok, ov;
    ok.x = f2bf(mk.x * xc.x + (1.f - mk.x) * xp.x);
    ok.y = f2bf(mk.y * xc.y + (1.f - mk.y) * xp.y);
    ok.z = f2bf(mk.z * xc.z + (1.f - mk.z) * xp.z);
    ok.w = f2bf(mk.w * xc.w + (1.f - mk.w) * xp.w);
    ov.x = f2bf(mv.x * xc.x + (1.f - mv.x) * xp.x);
    ov.y = f2bf(mv.y * xc.y + (1.f - mv.y) * xp.y);
    ov.z = f2bf(mv.z * xc.z + (1.f - mv.z) * xp.z);
    ov.w = f2bf(mv.w * xc.w + (1.f - mv.w) * xp.w);
    ((ushort4*)xk)[i] = ok;
    ((ushort4*)xv)[i] = ov;
}

// ---------------------------------------------------------------------------
// 2. cast + transpose weights f32[K][N] -> bf16[N][K]; 3 matrices via grid z
// ---------------------------------------------------------------------------
__global__ __launch_bounds__(256) void cast_transpose_k(
    const float* __restrict__ w0, const float* __restrict__ w1,
    const float* __restrict__ w2,
    unsigned short* __restrict__ o0, unsigned short* __restrict__ o1,
    unsigned short* __restrict__ o2)
{
    const float* in = blockIdx.z == 0 ? w0 : (blockIdx.z == 1 ? w1 : w2);
    unsigned short* out = blockIdx.z == 0 ? o0 : (blockIdx.z == 1 ? o1 : o2);
    __shared__ float tile[32][33];
    int bx = blockIdx.x * 32, by = blockIdx.y * 32;
    int tx = threadIdx.x, ty = threadIdx.y;           // block (32, 8)
    #pragma unroll
    for (int i = 0; i < 32; i += 8)
        tile[ty + i][tx] = in[(size_t)(by + ty + i) * E_DIM + bx + tx];
    __syncthreads();
    #pragma unroll
    for (int i = 0; i < 32; i += 8)
        out[(size_t)(bx + ty + i) * E_DIM + by + tx] = f2bf(tile[tx][ty + i]);
}

// ---------------------------------------------------------------------------
// 3. bf16 MFMA GEMM: C[M][N] = A[M][K] bf16 @ (BT[N][K] bf16)^T
//    128x128 tile, BK=64 (128B rows = bank-stride aligned), XOR-8 chunk
//    swizzle -> conflict-free ds_read_b128 (verified: conflicts 4.19M -> 0).
//    OutT = float (f32 C) or unsigned short (bf16 C, halves write traffic).
// ---------------------------------------------------------------------------
#define BM 128
#define BN 128
#define BK 64

template <typename OutT>
__global__ __launch_bounds__(256) void gemm_bf16_bt(
    const unsigned short* __restrict__ A,
    const unsigned short* __restrict__ BT,
    OutT* __restrict__ C, int M, int N, int K)
{
    __shared__ __align__(16) unsigned short As[BM * BK];  // 16 KiB, 128B rows
    __shared__ __align__(16) unsigned short Bs[BN * BK];  // 16 KiB
    const int tid  = threadIdx.x;
    const int wave = tid >> 6, lane = tid & 63;
    const int bm = blockIdx.x * BM, bn = blockIdx.y * BN;
    const int wr = (wave >> 1) * 64, wc = (wave & 1) * 64; // wave's 64x64 region
    const int lrow = lane & 15, lq = lane >> 4;

    f32x4 acc[4][4];
    #pragma unroll
    for (int i = 0; i < 4; ++i)
        #pragma unroll
        for (int j = 0; j < 4; ++j)
            acc[i][j] = (f32x4){0.f, 0.f, 0.f, 0.f};

    const int nk = K / BK;
    for (int kt = 0; kt < nk; ++kt) {
        __syncthreads();                               // prev reads done
        const int kk = kt * BK;
        // stage A and B tiles: 1024 chunks of 16B each per matrix.
        // lds chunk idx = s*256 + wave*64 + lane (HW: wave base + lane*16).
        // row = idx>>3, lds col c' = idx&7, global chunk gc = c' ^ (row&7).
        #pragma unroll
        for (int s = 0; s < 4; ++s) {
            int idx = s * 256 + wave * 64 + lane;
            int r   = idx >> 3;
            int gc  = (idx & 7) ^ (r & 7);
            const char* ga = (const char*)(A  + (size_t)(bm + r) * K + kk) + gc * 16;
            const char* gb = (const char*)(BT + (size_t)(bn + r) * K + kk) + gc * 16;
            char* la = (char*)As + s * 4096 + wave * 1024;   // wave-uniform
            char* lb = (char*)Bs + s * 4096 + wave * 1024;
            __builtin_amdgcn_global_load_lds(
                (const __attribute__((address_space(1))) unsigned int*)ga,
                (__attribute__((address_space(3))) unsigned int*)la, 16, 0, 0);
            __builtin_amdgcn_global_load_lds(
                (const __attribute__((address_space(1))) unsigned int*)gb,
                (__attribute__((address_space(3))) unsigned int*)lb, 16, 0, 0);
        }
        __syncthreads();                               // drains vmcnt + barrier

        #pragma unroll
        for (int h = 0; h < 2; ++h) {                  // two K=32 halves
            bf16x8 af[4], bf[4];
            #pragma unroll
            for (int i = 0; i < 4; ++i) {
                int R = wr + i * 16 + lrow;
                af[i] = *(const bf16x8*)&As[R * BK + (((h << 2) | lq) ^ (R & 7)) * 8];
            }
            #pragma unroll
            for (int j = 0; j < 4; ++j) {
                int R = wc + j * 16 + lrow;
                bf[j] = *(const bf16x8*)&Bs[R * BK + (((h << 2) | lq) ^ (R & 7)) * 8];
            }
            #pragma unroll
            for (int i = 0; i < 4; ++i)
                #pragma unroll
                for (int j = 0; j < 4; ++j)
                    acc[i][j] = __builtin_amdgcn_mfma_f32_16x16x32_bf16(
                        af[i], bf[j], acc[i][j], 0, 0, 0);
        }
    }

    // epilogue: D[row=(lane>>4)*4+r][col=lane&15] per 16x16 subtile
    #pragma unroll
    for (int i = 0; i < 4; ++i)
        #pragma unroll
        for (int j = 0; j < 4; ++j)
            #pragma unroll
            for (int r = 0; r < 4; ++r) {
                int row = bm + wr + i * 16 + lq * 4 + r;
                int col = bn + wc + j * 16 + lrow;
                if constexpr (sizeof(OutT) == 2)
                    C[(size_t)row * N + col] = f2bf(acc[i][j][r]);
                else
                    C[(size_t)row * N + col] = acc[i][j][r];
            }
}

// ---------------------------------------------------------------------------
// 4. WKV associative scan, chunked 3-pass. Element: (v,1,w,k); combine:
//    p'=max(p_l+w_r, p_r); a'=a_l*e1+a_r*e2; b'=b_l*e1+b_r*e2
//    k,v stored bf16 (packed pairs); each thread handles 2 adjacent channels.
// ---------------------------------------------------------------------------
__device__ __forceinline__ void wkv_step(float& a, float& b, float& p,
                                         float kt, float vt, float w)
{
    float pw = p + w;
    float pn = fmaxf(pw, kt);
    float e1 = __expf(pw - pn), e2 = __expf(kt - pn);
    a = a * e1 + vt * e2;
    b = b * e1 + e2;
    p = pn;
}

__global__ __launch_bounds__(256) void scan_pass1(
    const unsigned int* __restrict__ k2, const unsigned int* __restrict__ v2,
    const float* __restrict__ tdec,
    float2* __restrict__ sA, float2* __restrict__ sB, float2* __restrict__ sP)
{
    int g   = blockIdx.x * 256 + threadIdx.x;  // pair index: c*(BE/2)+ch2
    int ch2 = g & (BE / 2 - 1);
    int c   = g >> 12;
    float2 w2 = ((const float2*)tdec)[ch2 & (E_DIM / 2 - 1)];
    size_t idx = (size_t)c * CLEN * (BE / 2) + ch2;
    unsigned int ku = k2[idx], vu = v2[idx];
    float a0 = bf_lo(vu), b0 = 1.f, p0 = bf_lo(ku);
    float a1 = bf_hi(vu), b1 = 1.f, p1 = bf_hi(ku);
    for (int j = 1; j < CLEN; ++j) {
        idx += BE / 2;
        ku = k2[idx]; vu = v2[idx];
        wkv_step(a0, b0, p0, bf_lo(ku), bf_lo(vu), w2.x);
        wkv_step(a1, b1, p1, bf_hi(ku), bf_hi(vu), w2.y);
    }
    sA[g] = make_float2(a0, a1);
    sB[g] = make_float2(b0, b1);
    sP[g] = make_float2(p0, p1);
}

// Wave-parallel cross-chunk exclusive scan: block = 64 channels x 64 chunks.
// LDS transpose -> lane-per-chunk Hillis-Steele shuffle scan (6 steps).
__global__ __launch_bounds__(256) void scan_pass2(
    const float* __restrict__ tdec,
    float* __restrict__ sA, float* __restrict__ sB, float* __restrict__ sP)
{
    __shared__ float tA[64 * 65], tB[64 * 65], tP[64 * 65];
    const int t   = threadIdx.x;
    const int ch0 = blockIdx.x * 64;
    const int chl = t & 63;
    const int cq  = t >> 6;                    // 0..3
    #pragma unroll 4
    for (int cc = 0; cc < 16; ++cc) {
        int c = cq * 16 + cc;
        int idx = c * BE + ch0 + chl;
        tA[chl * 65 + c] = sA[idx];
        tB[chl * 65 + c] = sB[idx];
        tP[chl * 65 + c] = sP[idx];
    }
    __syncthreads();
    const int lane = t & 63, wave = t >> 6;
    for (int i = 0; i < 16; ++i) {
        int ch = wave * 16 + i;                // local channel 0..63
        float w = tdec[(ch0 + ch) & (E_DIM - 1)];
        float a = tA[ch * 65 + lane];
        float b = tB[ch * 65 + lane];
        float p = tP[ch * 65 + lane];
        float W = (float)CLEN * w;             // accumulated decay of this span
        #pragma unroll
        for (int d = 1; d < 64; d <<= 1) {
            float a_l = __shfl_up(a, d);
            float b_l = __shfl_up(b, d);
            float p_l = __shfl_up(p, d);
            float W_l = __shfl_up(W, d);
            if (lane >= d) {
                float pw = p_l + W;            // left.p + right.Wacc
                float pn = fmaxf(pw, p);
                float e1 = __expf(pw - pn), e2 = __expf(p - pn);
                a = a_l * e1 + a * e2;
                b = b_l * e1 + b * e2;
                p = pn;
                W = W_l + W;
            }
        }
        // exclusive = inclusive shifted up by one; identity at chunk 0
        float ea = __shfl_up(a, 1);
        float eb = __shfl_up(b, 1);
        float ep = __shfl_up(p, 1);
        if (lane == 0) { ea = 0.f; eb = 0.f; ep = -__builtin_inff(); }
        tA[ch * 65 + lane] = ea;
        tB[ch * 65 + lane] = eb;
        tP[ch * 65 + lane] = ep;
    }
    __syncthreads();
    #pragma unroll 4
    for (int cc = 0; cc < 16; ++cc) {
        int c = cq * 16 + cc;
        int idx = c * BE + ch0 + chl;
        sA[idx] = tA[chl * 65 + c];
        sB[idx] = tB[chl * 65 + c];
        sP[idx] = tP[chl * 65 + c];
    }
}

__global__ __launch_bounds__(256) void scan_pass3(
    const unsigned int* __restrict__ k2, const unsigned int* __restrict__ v2,
    const float* __restrict__ tdec, const float* __restrict__ tfir,
    const float2* __restrict__ sA, const float2* __restrict__ sB,
    const float2* __restrict__ sP, unsigned int* __restrict__ rwkv2)
{
    int g   = blockIdx.x * 256 + threadIdx.x;  // pair index
    int ch2 = g & (BE / 2 - 1);
    int c   = g >> 12;
    int e2  = ch2 & (E_DIM / 2 - 1);
    float2 w2 = ((const float2*)tdec)[e2];
    float2 f2 = ((const float2*)tfir)[e2];
    float u20 = f2.x + w2.x, u21 = f2.y + w2.y;   // time_first + time_decay
    float2 av = sA[g], bv = sB[g], pv = sP[g];     // carry-in (excl prefix)
    float a0 = av.x, b0 = bv.x, p0 = pv.x;
    float a1 = av.y, b1 = bv.y, p1 = pv.y;
    size_t idx = (size_t)c * CLEN * (BE / 2) + ch2;
    for (int j = 0; j < CLEN; ++j) {
        unsigned int ku = k2[idx], vu = v2[idx];
        float kt0 = bf_lo(ku), vt0 = bf_lo(vu);
        float kt1 = bf_hi(ku), vt1 = bf_hi(vu);
        wkv_step(a0, b0, p0, kt0, vt0, w2.x);
        wkv_step(a1, b1, p1, kt1, vt1, w2.y);
        // bonus-mix output: exp_mix_frac(p, k+u+w, a, b, v, 1)
        float kb0 = kt0 + u20, kb1 = kt1 + u21;
        float q0 = fmaxf(p0, kb0), q1 = fmaxf(p1, kb1);
        float g0 = __expf(p0 - q0), h0 = __expf(kb0 - q0);
        float g1 = __expf(p1 - q1), h1 = __expf(kb1 - q1);
        float r0 = (a0 * g0 + vt0 * h0) / (b0 * g0 + h0);
        float r1 = (a1 * g1 + vt1 * h1) / (b1 * g1 + h1);
        rwkv2[idx] = (unsigned int)f2bf(r0) | ((unsigned int)f2bf(r1) << 16);
        idx += BE / 2;
    }
}

// ---------------------------------------------------------------------------
extern "C" void kernel_launch(void* const* d_in, const int* in_sizes, int n_in,
                              void* d_out, int out_size, void* d_ws, size_t ws_size,
                              hipStream_t stream)
{
    const float* x     = (const float*)d_in[0];
    const float* tmrkv = (const float*)d_in[1];
    const float* Wk    = (const float*)d_in[2];
    const float* Wv    = (const float*)d_in[3];
    const float* tdec  = (const float*)d_in[4];
    const float* tfir  = (const float*)d_in[5];
    const float* Wout  = (const float*)d_in[6];
    float* out = (float*)d_out;

    // workspace layout (all bf16 now): xk | xv | k | v | WkT | WvT | WoutT
    // reuse: rwkv -> xk space (dead after gemm_k); scan scratch -> xv space
    char* ws = (char*)d_ws;
    const size_t SZ_BF = (size_t)M_ROWS * E_DIM * 2;   // 32 MiB
    unsigned short* xk   = (unsigned short*)(ws);
    unsigned short* xv   = (unsigned short*)(ws + SZ_BF);
    unsigned short* kbuf = (unsigned short*)(ws + 2 * SZ_BF);
    unsigned short* vbuf = (unsigned short*)(ws + 3 * SZ_BF);
    unsigned short* WkT  = (unsigned short*)(ws + 4 * SZ_BF);
    unsigned short* WvT  = WkT + (size_t)E_DIM * E_DIM;
    unsigned short* WoutT= WvT + (size_t)E_DIM * E_DIM;
    float* sA = (float*)xv;                    // 2 MiB each, xv dead by then
    float* sB = sA + (size_t)NCHUNK * BE;
    float* sP = sB + (size_t)NCHUNK * BE;
    unsigned short* rwkv = xk;                 // xk dead after gemm_k

    // 1. mix (reads x; writes xk, xv bf16)
    mix_kernel<<<(M_ROWS * E_DIM / 4) / 256, 256, 0, stream>>>(x, tmrkv, xk, xv);

    // 2. weight casts (f32 [K][N] -> bf16 [N][K]), one launch for all three
    dim3 tb(32, 8), tg(E_DIM / 32, E_DIM / 32, 3);
    cast_transpose_k<<<tg, tb, 0, stream>>>(Wk, Wv, Wout, WkT, WvT, WoutT);

    // 3. k = xk @ Wk, v = xv @ Wv  (bf16 out — halves write + scan read traffic)
    dim3 gg(M_ROWS / BM, E_DIM / BN);
    gemm_bf16_bt<unsigned short><<<gg, 256, 0, stream>>>(xk, WkT, kbuf,
                                                         M_ROWS, E_DIM, E_DIM);
    gemm_bf16_bt<unsigned short><<<gg, 256, 0, stream>>>(xv, WvT, vbuf,
                                                         M_ROWS, E_DIM, E_DIM);

    // 4. chunked associative scan -> rwkv bf16 (2 channels per thread)
    scan_pass1<<<(NCHUNK * BE / 2) / 256, 256, 0, stream>>>(
        (const unsigned int*)kbuf, (const unsigned int*)vbuf, tdec,
        (float2*)sA, (float2*)sB, (float2*)sP);
    scan_pass2<<<BE / 64, 256, 0, stream>>>(tdec, sA, sB, sP);
    scan_pass3<<<(NCHUNK * BE / 2) / 256, 256, 0, stream>>>(
        (const unsigned int*)kbuf, (const unsigned int*)vbuf, tdec, tfir,
        (const float2*)sA, (const float2*)sB, (const float2*)sP,
        (unsigned int*)rwkv);

    // 5. out = rwkv @ Wout  (f32 out)
    gemm_bf16_bt<float><<<gg, 256, 0, stream>>>(rwkv, WoutT, out,
                                                M_ROWS, E_DIM, E_DIM);
}

// Round 4
// 327.950 us; speedup vs baseline: 1.1551x; 1.0275x over previous
//
#include <hip/hip_runtime.h>
#include <stdint.h>

// Problem constants (fixed shapes from setup_inputs)
#define S_LEN  2048
#define B_DIM  8
#define E_DIM  1024
#define BE     (B_DIM * E_DIM)      // 8192  (one time-step's elements)
#define M_ROWS (S_LEN * B_DIM)      // 16384 (GEMM M)
#define NCHUNK 64
#define CLEN   (S_LEN / NCHUNK)     // 32

typedef __attribute__((ext_vector_type(8))) short bf16x8;  // 8 bf16 (4 VGPRs)
typedef __attribute__((ext_vector_type(4))) float f32x4;

__device__ __forceinline__ unsigned short f2bf(float f) {
    // round-to-nearest-even f32 -> bf16 (no NaN inputs expected)
    unsigned int u = __float_as_uint(f);
    u += 0x7FFFu + ((u >> 16) & 1u);
    return (unsigned short)(u >> 16);
}
__device__ __forceinline__ float bf_lo(unsigned int u) {
    return __uint_as_float(u << 16);
}
__device__ __forceinline__ float bf_hi(unsigned int u) {
    return __uint_as_float(u & 0xFFFF0000u);
}

// ---------------------------------------------------------------------------
// 1. token-shift mix: xk = mk*x + (1-mk)*x_prev, xv likewise; output bf16.
//    8 elements/thread: 2x float4 loads, 1x ushort8 (16B) store per output.
// ---------------------------------------------------------------------------
__global__ __launch_bounds__(256) void mix_kernel(
    const float* __restrict__ x, const float* __restrict__ tmrkv,
    unsigned short* __restrict__ xk, unsigned short* __restrict__ xv)
{
    int i = blockIdx.x * 256 + threadIdx.x;           // 8-elem group index
    const float4* x4 = (const float4*)x;
    float4 xc[2], xp[2];
    xc[0] = x4[2 * i];
    xc[1] = x4[2 * i + 1];
    if (i >= BE / 8) {
        xp[0] = x4[2 * i - BE / 4];
        xp[1] = x4[2 * i + 1 - BE / 4];
    } else {
        xp[0] = make_float4(0.f, 0.f, 0.f, 0.f);
        xp[1] = make_float4(0.f, 0.f, 0.f, 0.f);
    }
    int e4 = (2 * i) & (E_DIM / 4 - 1);
    ushort4 ok[2], ov[2];
    #pragma unroll
    for (int h = 0; h < 2; ++h) {
        float4 mk = ((const float4*)(tmrkv + E_DIM))[e4 + h];
        float4 mv = ((const float4*)(tmrkv + 2 * E_DIM))[e4 + h];
        ok[h].x = f2bf(mk.x * xc[h].x + (1.f - mk.x) * xp[h].x);
        ok[h].y = f2bf(mk.y * xc[h].y + (1.f - mk.y) * xp[h].y);
        ok[h].z = f2bf(mk.z * xc[h].z + (1.f - mk.z) * xp[h].z);
        ok[h].w = f2bf(mk.w * xc[h].w + (1.f - mk.w) * xp[h].w);
        ov[h].x = f2bf(mv.x * xc[h].x + (1.f - mv.x) * xp[h].x);
        ov[h].y = f2bf(mv.y * xc[h].y + (1.f - mv.y) * xp[h].y);
        ov[h].z = f2bf(mv.z * xc[h].z + (1.f - mv.z) * xp[h].z);
        ov[h].w = f2bf(mv.w * xc[h].w + (1.f - mv.w) * xp[h].w);
    }
    ((ushort4*)xk)[2 * i]     = ok[0];
    ((ushort4*)xk)[2 * i + 1] = ok[1];
    ((ushort4*)xv)[2 * i]     = ov[0];
    ((ushort4*)xv)[2 * i + 1] = ov[1];
}

// ---------------------------------------------------------------------------
// 2. cast + transpose weights f32[K][N] -> bf16[N][K]; 3 matrices via grid z
// ---------------------------------------------------------------------------
__global__ __launch_bounds__(256) void cast_transpose_k(
    const float* __restrict__ w0, const float* __restrict__ w1,
    const float* __restrict__ w2,
    unsigned short* __restrict__ o0, unsigned short* __restrict__ o1,
    unsigned short* __restrict__ o2)
{
    const float* in = blockIdx.z == 0 ? w0 : (blockIdx.z == 1 ? w1 : w2);
    unsigned short* out = blockIdx.z == 0 ? o0 : (blockIdx.z == 1 ? o1 : o2);
    __shared__ float tile[32][33];
    int bx = blockIdx.x * 32, by = blockIdx.y * 32;
    int tx = threadIdx.x, ty = threadIdx.y;           // block (32, 8)
    #pragma unroll
    for (int i = 0; i < 32; i += 8)
        tile[ty + i][tx] = in[(size_t)(by + ty + i) * E_DIM + bx + tx];
    __syncthreads();
    #pragma unroll
    for (int i = 0; i < 32; i += 8)
        out[(size_t)(bx + ty + i) * E_DIM + by + tx] = f2bf(tile[tx][ty + i]);
}

// ---------------------------------------------------------------------------
// 3. bf16 MFMA GEMM: C[M][N] = A[M][K] bf16 @ (BT[N][K] bf16)^T
//    128x128 tile, BK=64 (128B rows = bank-stride aligned), XOR-8 chunk
//    swizzle -> conflict-free ds_read_b128 (verified: conflicts 4.19M -> 0).
//    Dual-problem variant: blockIdx.z selects (A,B,C) set — used to run the
//    k and v GEMMs as one dispatch.
// ---------------------------------------------------------------------------
#define BM 128
#define BN 128
#define BK 64

template <typename OutT>
__device__ __forceinline__ void gemm_body(
    const unsigned short* __restrict__ A,
    const unsigned short* __restrict__ BT,
    OutT* __restrict__ C, int M, int N, int K)
{
    __shared__ __align__(16) unsigned short As[BM * BK];  // 16 KiB, 128B rows
    __shared__ __align__(16) unsigned short Bs[BN * BK];  // 16 KiB
    const int tid  = threadIdx.x;
    const int wave = tid >> 6, lane = tid & 63;
    const int bm = blockIdx.x * BM, bn = blockIdx.y * BN;
    const int wr = (wave >> 1) * 64, wc = (wave & 1) * 64; // wave's 64x64 region
    const int lrow = lane & 15, lq = lane >> 4;

    f32x4 acc[4][4];
    #pragma unroll
    for (int i = 0; i < 4; ++i)
        #pragma unroll
        for (int j = 0; j < 4; ++j)
            acc[i][j] = (f32x4){0.f, 0.f, 0.f, 0.f};

    const int nk = K / BK;
    for (int kt = 0; kt < nk; ++kt) {
        __syncthreads();                               // prev reads done
        const int kk = kt * BK;
        // stage A and B tiles: 1024 chunks of 16B each per matrix.
        // lds chunk idx = s*256 + wave*64 + lane (HW: wave base + lane*16).
        // row = idx>>3, lds col c' = idx&7, global chunk gc = c' ^ (row&7).
        #pragma unroll
        for (int s = 0; s < 4; ++s) {
            int idx = s * 256 + wave * 64 + lane;
            int r   = idx >> 3;
            int gc  = (idx & 7) ^ (r & 7);
            const char* ga = (const char*)(A  + (size_t)(bm + r) * K + kk) + gc * 16;
            const char* gb = (const char*)(BT + (size_t)(bn + r) * K + kk) + gc * 16;
            char* la = (char*)As + s * 4096 + wave * 1024;   // wave-uniform
            char* lb = (char*)Bs + s * 4096 + wave * 1024;
            __builtin_amdgcn_global_load_lds(
                (const __attribute__((address_space(1))) unsigned int*)ga,
                (__attribute__((address_space(3))) unsigned int*)la, 16, 0, 0);
            __builtin_amdgcn_global_load_lds(
                (const __attribute__((address_space(1))) unsigned int*)gb,
                (__attribute__((address_space(3))) unsigned int*)lb, 16, 0, 0);
        }
        __syncthreads();                               // drains vmcnt + barrier

        #pragma unroll
        for (int h = 0; h < 2; ++h) {                  // two K=32 halves
            bf16x8 af[4], bf[4];
            #pragma unroll
            for (int i = 0; i < 4; ++i) {
                int R = wr + i * 16 + lrow;
                af[i] = *(const bf16x8*)&As[R * BK + (((h << 2) | lq) ^ (R & 7)) * 8];
            }
            #pragma unroll
            for (int j = 0; j < 4; ++j) {
                int R = wc + j * 16 + lrow;
                bf[j] = *(const bf16x8*)&Bs[R * BK + (((h << 2) | lq) ^ (R & 7)) * 8];
            }
            #pragma unroll
            for (int i = 0; i < 4; ++i)
                #pragma unroll
                for (int j = 0; j < 4; ++j)
                    acc[i][j] = __builtin_amdgcn_mfma_f32_16x16x32_bf16(
                        af[i], bf[j], acc[i][j], 0, 0, 0);
        }
    }

    // epilogue: D[row=(lane>>4)*4+r][col=lane&15] per 16x16 subtile
    #pragma unroll
    for (int i = 0; i < 4; ++i)
        #pragma unroll
        for (int j = 0; j < 4; ++j)
            #pragma unroll
            for (int r = 0; r < 4; ++r) {
                int row = bm + wr + i * 16 + lq * 4 + r;
                int col = bn + wc + j * 16 + lrow;
                if constexpr (sizeof(OutT) == 2)
                    C[(size_t)row * N + col] = f2bf(acc[i][j][r]);
                else
                    C[(size_t)row * N + col] = acc[i][j][r];
            }
}

__global__ __launch_bounds__(256) void gemm_kv(
    const unsigned short* __restrict__ A0, const unsigned short* __restrict__ B0,
    unsigned short* __restrict__ C0,
    const unsigned short* __restrict__ A1, const unsigned short* __restrict__ B1,
    unsigned short* __restrict__ C1, int M, int N, int K)
{
    if (blockIdx.z == 0) gemm_body<unsigned short>(A0, B0, C0, M, N, K);
    else                 gemm_body<unsigned short>(A1, B1, C1, M, N, K);
}

__global__ __launch_bounds__(256) void gemm_out(
    const unsigned short* __restrict__ A, const unsigned short* __restrict__ BT,
    float* __restrict__ C, int M, int N, int K)
{
    gemm_body<float>(A, BT, C, M, N, K);
}

// ---------------------------------------------------------------------------
// 4. WKV associative scan, chunked 3-pass. Element: (v,1,w,k); combine:
//    p'=max(p_l+w_r, p_r); a'=a_l*e1+a_r*e2; b'=b_l*e1+b_r*e2
//    k,v stored bf16; each thread handles 4 adjacent channels (uint2 = 8B).
// ---------------------------------------------------------------------------
__device__ __forceinline__ void wkv_step(float& a, float& b, float& p,
                                         float kt, float vt, float w)
{
    float pw = p + w;
    float pn = fmaxf(pw, kt);
    float e1 = __expf(pw - pn), e2 = __expf(kt - pn);
    a = a * e1 + vt * e2;
    b = b * e1 + e2;
    p = pn;
}

#define Q_PER_T (BE / 4)            // 2048 quad-groups per time-step

__global__ __launch_bounds__(256) void scan_pass1(
    const uint2* __restrict__ k4, const uint2* __restrict__ v4,
    const float* __restrict__ tdec,
    float4* __restrict__ sA, float4* __restrict__ sB, float4* __restrict__ sP)
{
    int g = blockIdx.x * 256 + threadIdx.x;    // quad index: c*Q_PER_T + q
    int q = g & (Q_PER_T - 1);
    int c = g >> 11;
    float4 w4 = ((const float4*)tdec)[q & (E_DIM / 4 - 1)];
    size_t idx = (size_t)c * CLEN * Q_PER_T + q;
    uint2 ku = k4[idx], vu = v4[idx];
    float a0 = bf_lo(vu.x), b0 = 1.f, p0 = bf_lo(ku.x);
    float a1 = bf_hi(vu.x), b1 = 1.f, p1 = bf_hi(ku.x);
    float a2 = bf_lo(vu.y), b2 = 1.f, p2 = bf_lo(ku.y);
    float a3 = bf_hi(vu.y), b3 = 1.f, p3 = bf_hi(ku.y);
    for (int j = 1; j < CLEN; ++j) {
        idx += Q_PER_T;
        ku = k4[idx]; vu = v4[idx];
        wkv_step(a0, b0, p0, bf_lo(ku.x), bf_lo(vu.x), w4.x);
        wkv_step(a1, b1, p1, bf_hi(ku.x), bf_hi(vu.x), w4.y);
        wkv_step(a2, b2, p2, bf_lo(ku.y), bf_lo(vu.y), w4.z);
        wkv_step(a3, b3, p3, bf_hi(ku.y), bf_hi(vu.y), w4.w);
    }
    sA[g] = make_float4(a0, a1, a2, a3);
    sB[g] = make_float4(b0, b1, b2, b3);
    sP[g] = make_float4(p0, p1, p2, p3);
}

// Wave-parallel cross-chunk exclusive scan: block = 64 channels x 64 chunks.
// LDS transpose -> lane-per-chunk Hillis-Steele shuffle scan (6 steps).
__global__ __launch_bounds__(256) void scan_pass2(
    const float* __restrict__ tdec,
    float* __restrict__ sA, float* __restrict__ sB, float* __restrict__ sP)
{
    __shared__ float tA[64 * 65], tB[64 * 65], tP[64 * 65];
    const int t   = threadIdx.x;
    const int ch0 = blockIdx.x * 64;
    const int chl = t & 63;
    const int cq  = t >> 6;                    // 0..3
    #pragma unroll 4
    for (int cc = 0; cc < 16; ++cc) {
        int c = cq * 16 + cc;
        int idx = c * BE + ch0 + chl;
        tA[chl * 65 + c] = sA[idx];
        tB[chl * 65 + c] = sB[idx];
        tP[chl * 65 + c] = sP[idx];
    }
    __syncthreads();
    const int lane = t & 63, wave = t >> 6;
    for (int i = 0; i < 16; ++i) {
        int ch = wave * 16 + i;                // local channel 0..63
        float w = tdec[(ch0 + ch) & (E_DIM - 1)];
        float a = tA[ch * 65 + lane];
        float b = tB[ch * 65 + lane];
        float p = tP[ch * 65 + lane];
        float W = (float)CLEN * w;             // accumulated decay of this span
        #pragma unroll
        for (int d = 1; d < 64; d <<= 1) {
            float a_l = __shfl_up(a, d);
            float b_l = __shfl_up(b, d);
            float p_l = __shfl_up(p, d);
            float W_l = __shfl_up(W, d);
            if (lane >= d) {
                float pw = p_l + W;            // left.p + right.Wacc
                float pn = fmaxf(pw, p);
                float e1 = __expf(pw - pn), e2 = __expf(p - pn);
                a = a_l * e1 + a * e2;
                b = b_l * e1 + b * e2;
                p = pn;
                W = W_l + W;
            }
        }
        // exclusive = inclusive shifted up by one; identity at chunk 0
        float ea = __shfl_up(a, 1);
        float eb = __shfl_up(b, 1);
        float ep = __shfl_up(p, 1);
        if (lane == 0) { ea = 0.f; eb = 0.f; ep = -__builtin_inff(); }
        tA[ch * 65 + lane] = ea;
        tB[ch * 65 + lane] = eb;
        tP[ch * 65 + lane] = ep;
    }
    __syncthreads();
    #pragma unroll 4
    for (int cc = 0; cc < 16; ++cc) {
        int c = cq * 16 + cc;
        int idx = c * BE + ch0 + chl;
        sA[idx] = tA[chl * 65 + c];
        sB[idx] = tB[chl * 65 + c];
        sP[idx] = tP[chl * 65 + c];
    }
}

__global__ __launch_bounds__(256) void scan_pass3(
    const uint2* __restrict__ k4, const uint2* __restrict__ v4,
    const float* __restrict__ tdec, const float* __restrict__ tfir,
    const float4* __restrict__ sA, const float4* __restrict__ sB,
    const float4* __restrict__ sP, uint2* __restrict__ rwkv4)
{
    int g = blockIdx.x * 256 + threadIdx.x;    // quad index
    int q = g & (Q_PER_T - 1);
    int c = g >> 11;
    int e4 = q & (E_DIM / 4 - 1);
    float4 w4 = ((const float4*)tdec)[e4];
    float4 f4 = ((const float4*)tfir)[e4];
    float u0 = f4.x + w4.x, u1 = f4.y + w4.y;
    float u2 = f4.z + w4.z, u3 = f4.w + w4.w;
    float4 av = sA[g], bv = sB[g], pv = sP[g]; // carry-in (excl prefix)
    float a0 = av.x, b0 = bv.x, p0 = pv.x;
    float a1 = av.y, b1 = bv.y, p1 = pv.y;
    float a2 = av.z, b2 = bv.z, p2 = pv.z;
    float a3 = av.w, b3 = bv.w, p3 = pv.w;
    size_t idx = (size_t)c * CLEN * Q_PER_T + q;
    for (int j = 0; j < CLEN; ++j) {
        uint2 ku = k4[idx], vu = v4[idx];
        float kt0 = bf_lo(ku.x), vt0 = bf_lo(vu.x);
        float kt1 = bf_hi(ku.x), vt1 = bf_hi(vu.x);
        float kt2 = bf_lo(ku.y), vt2 = bf_lo(vu.y);
        float kt3 = bf_hi(ku.y), vt3 = bf_hi(vu.y);
        wkv_step(a0, b0, p0, kt0, vt0, w4.x);
        wkv_step(a1, b1, p1, kt1, vt1, w4.y);
        wkv_step(a2, b2, p2, kt2, vt2, w4.z);
        wkv_step(a3, b3, p3, kt3, vt3, w4.w);
        // bonus-mix output: exp_mix_frac(p, k+u+w, a, b, v, 1)
        float kb0 = kt0 + u0, kb1 = kt1 + u1, kb2 = kt2 + u2, kb3 = kt3 + u3;
        float q0 = fmaxf(p0, kb0), q1 = fmaxf(p1, kb1);
        float q2 = fmaxf(p2, kb2), q3 = fmaxf(p3, kb3);
        float g0 = __expf(p0 - q0), h0 = __expf(kb0 - q0);
        float g1 = __expf(p1 - q1), h1 = __expf(kb1 - q1);
        float g2 = __expf(p2 - q2), h2 = __expf(kb2 - q2);
        float g3 = __expf(p3 - q3), h3 = __expf(kb3 - q3);
        float r0 = (a0 * g0 + vt0 * h0) / (b0 * g0 + h0);
        float r1 = (a1 * g1 + vt1 * h1) / (b1 * g1 + h1);
        float r2 = (a2 * g2 + vt2 * h2) / (b2 * g2 + h2);
        float r3 = (a3 * g3 + vt3 * h3) / (b3 * g3 + h3);
        uint2 o;
        o.x = (unsigned int)f2bf(r0) | ((unsigned int)f2bf(r1) << 16);
        o.y = (unsigned int)f2bf(r2) | ((unsigned int)f2bf(r3) << 16);
        rwkv4[idx] = o;
        idx += Q_PER_T;
    }
}

// ---------------------------------------------------------------------------
extern "C" void kernel_launch(void* const* d_in, const int* in_sizes, int n_in,
                              void* d_out, int out_size, void* d_ws, size_t ws_size,
                              hipStream_t stream)
{
    const float* x     = (const float*)d_in[0];
    const float* tmrkv = (const float*)d_in[1];
    const float* Wk    = (const float*)d_in[2];
    const float* Wv    = (const float*)d_in[3];
    const float* tdec  = (const float*)d_in[4];
    const float* tfir  = (const float*)d_in[5];
    const float* Wout  = (const float*)d_in[6];
    float* out = (float*)d_out;

    // workspace layout (all bf16): xk | xv | k | v | WkT | WvT | WoutT
    // reuse: rwkv -> xk space (dead after gemm_kv); scan scratch -> xv space
    char* ws = (char*)d_ws;
    const size_t SZ_BF = (size_t)M_ROWS * E_DIM * 2;   // 32 MiB
    unsigned short* xk   = (unsigned short*)(ws);
    unsigned short* xv   = (unsigned short*)(ws + SZ_BF);
    unsigned short* kbuf = (unsigned short*)(ws + 2 * SZ_BF);
    unsigned short* vbuf = (unsigned short*)(ws + 3 * SZ_BF);
    unsigned short* WkT  = (unsigned short*)(ws + 4 * SZ_BF);
    unsigned short* WvT  = WkT + (size_t)E_DIM * E_DIM;
    unsigned short* WoutT= WvT + (size_t)E_DIM * E_DIM;
    float* sA = (float*)xv;                    // 2 MiB each, xv dead by then
    float* sB = sA + (size_t)NCHUNK * BE;
    float* sP = sB + (size_t)NCHUNK * BE;
    unsigned short* rwkv = xk;                 // xk dead after gemm_kv

    // 1. mix (reads x; writes xk, xv bf16)
    mix_kernel<<<(M_ROWS * E_DIM / 8) / 256, 256, 0, stream>>>(x, tmrkv, xk, xv);

    // 2. weight casts (f32 [K][N] -> bf16 [N][K]), one launch for all three
    dim3 tb(32, 8), tg(E_DIM / 32, E_DIM / 32, 3);
    cast_transpose_k<<<tg, tb, 0, stream>>>(Wk, Wv, Wout, WkT, WvT, WoutT);

    // 3. k = xk @ Wk, v = xv @ Wv in ONE dispatch (bf16 out)
    dim3 gkv(M_ROWS / BM, E_DIM / BN, 2);
    gemm_kv<<<gkv, 256, 0, stream>>>(xk, WkT, kbuf, xv, WvT, vbuf,
                                     M_ROWS, E_DIM, E_DIM);

    // 4. chunked associative scan -> rwkv bf16 (4 channels per thread)
    scan_pass1<<<(NCHUNK * Q_PER_T) / 256, 256, 0, stream>>>(
        (const uint2*)kbuf, (const uint2*)vbuf, tdec,
        (float4*)sA, (float4*)sB, (float4*)sP);
    scan_pass2<<<BE / 64, 256, 0, stream>>>(tdec, sA, sB, sP);
    scan_pass3<<<(NCHUNK * Q_PER_T) / 256, 256, 0, stream>>>(
        (const uint2*)kbuf, (const uint2*)vbuf, tdec, tfir,
        (const float4*)sA, (const float4*)sB, (const float4*)sP,
        (uint2*)rwkv);

    // 5. out = rwkv @ Wout  (f32 out)
    dim3 gg(M_ROWS / BM, E_DIM / BN);
    gemm_out<<<gg, 256, 0, stream>>>(rwkv, WoutT, out, M_ROWS, E_DIM, E_DIM);
}